// Round 1
// baseline (313.919 us; speedup 1.0000x reference)
//
#include <hip/hip_runtime.h>
#include <stdint.h>

typedef _Float16 __attribute__((ext_vector_type(8))) f16x8;
typedef _Float16 __attribute__((ext_vector_type(4))) f16x4v;
typedef float __attribute__((ext_vector_type(4))) f32x4;

__device__ __forceinline__ f32x4 mfma16(f16x8 a, f16x8 b, f32x4 c) {
  return __builtin_amdgcn_mfma_f32_16x16x32_f16(a, b, c, 0, 0, 0);
}

// ---------------- conversions ----------------
__global__ __launch_bounds__(256) void k_cvt_f16(const float* __restrict__ in,
                                                 _Float16* __restrict__ out) {
  const int i = blockIdx.x * 256 + threadIdx.x;
  const float4 v = reinterpret_cast<const float4*>(in)[i];
  f16x4v o = { (_Float16)v.x, (_Float16)v.y, (_Float16)v.z, (_Float16)v.w };
  reinterpret_cast<f16x4v*>(out)[i] = o;
}

// W[1024][1024] f32 -> Wt[1024][1024] f16 with Wt[n][k] = W[k][n]
__global__ __launch_bounds__(256) void k_transpose_f16(const float* __restrict__ W,
                                                       _Float16* __restrict__ Wt) {
  __shared__ float tl[32][33];
  const int c0 = blockIdx.x * 32, r0 = blockIdx.y * 32;
  const int tx = threadIdx.x & 31, ty = threadIdx.x >> 5;  // 32 x 8
#pragma unroll
  for (int i = 0; i < 32; i += 8)
    tl[ty + i][tx] = W[(size_t)(r0 + ty + i) * 1024 + c0 + tx];
  __syncthreads();
#pragma unroll
  for (int i = 0; i < 32; i += 8)
    Wt[(size_t)(c0 + ty + i) * 1024 + r0 + tx] = (_Float16)tl[tx][ty + i];
}

// ---------------- GEMM: C[M][N] = A[M][K] @ Bt[N][K]^T ----------------
// MODE 0: f16 out, split into qk buffer (cols<2048, stride 2048) and
//         V^T buffer vt[b][dd][seq] (cols>=2048). N must be 3072.
// MODE 1: f32 out + bias, row stride N.
template <int MODE>
__global__ __launch_bounds__(256) void k_gemm(const _Float16* __restrict__ A,
                                              const _Float16* __restrict__ Bt,
                                              const float* __restrict__ bias,
                                              _Float16* __restrict__ qkout,
                                              _Float16* __restrict__ vtout,
                                              float* __restrict__ fout,
                                              int N, int K) {
  __shared__ _Float16 As[128][40];
  __shared__ _Float16 Bs[128][40];
  const int tile_n = blockIdx.x * 128;
  const int tile_m = blockIdx.y * 128;
  const int t = threadIdx.x;
  const int w = t >> 6, lane = t & 63;
  const int c16 = lane & 15, g = lane >> 4;
  const int wr = (w >> 1) * 64, wc = (w & 1) * 64;

  f32x4 acc[4][4] = {};

  const int r0 = t >> 2;         // 0..63
  const int kc = (t & 3) * 8;    // 0,8,16,24

  for (int k0 = 0; k0 < K; k0 += 32) {
    const uint4 a0 = *reinterpret_cast<const uint4*>(A + (size_t)(tile_m + r0) * K + k0 + kc);
    const uint4 a1 = *reinterpret_cast<const uint4*>(A + (size_t)(tile_m + 64 + r0) * K + k0 + kc);
    const uint4 b0 = *reinterpret_cast<const uint4*>(Bt + (size_t)(tile_n + r0) * K + k0 + kc);
    const uint4 b1 = *reinterpret_cast<const uint4*>(Bt + (size_t)(tile_n + 64 + r0) * K + k0 + kc);
    __syncthreads();
    *reinterpret_cast<uint4*>(&As[r0][kc]) = a0;
    *reinterpret_cast<uint4*>(&As[64 + r0][kc]) = a1;
    *reinterpret_cast<uint4*>(&Bs[r0][kc]) = b0;
    *reinterpret_cast<uint4*>(&Bs[64 + r0][kc]) = b1;
    __syncthreads();
    f16x8 af[4], bf[4];
#pragma unroll
    for (int i = 0; i < 4; ++i) {
      af[i] = *reinterpret_cast<const f16x8*>(&As[wr + i * 16 + c16][g * 8]);
      bf[i] = *reinterpret_cast<const f16x8*>(&Bs[wc + i * 16 + c16][g * 8]);
    }
#pragma unroll
    for (int i = 0; i < 4; ++i)
#pragma unroll
      for (int j = 0; j < 4; ++j) acc[i][j] = mfma16(af[i], bf[j], acc[i][j]);
  }

  // D layout: col = lane&15, row = (lane>>4)*4 + reg   [m89/m91 verified]
#pragma unroll
  for (int i = 0; i < 4; ++i) {
#pragma unroll
    for (int j = 0; j < 4; ++j) {
      const int colb = tile_n + wc + j * 16;
#pragma unroll
      for (int r = 0; r < 4; ++r) {
        const int row = tile_m + wr + i * 16 + g * 4 + r;
        const int col = colb + c16;
        const float v = acc[i][j][r];
        if constexpr (MODE == 0) {
          if (col < 2048) {
            qkout[(size_t)row * 2048 + col] = (_Float16)v;
          } else {
            const int dd = col - 2048;  // h*64 + d
            vtout[((size_t)(row >> 11) * 1024 + dd) * 2048 + (row & 2047)] = (_Float16)v;
          }
        } else {
          fout[(size_t)row * N + col] = v + bias[col];
        }
      }
    }
  }
}

// ---------------- causal flash attention ----------------
// qk: [b*2048][2048] f16 (Q cols 0..1023, K cols 1024..2047, col = h*64+d)
// vt: [b][h*64+d][2048] f16 (V transposed)
// ctx: [b*2048][1024] f16
__global__ __launch_bounds__(256) void k_attn(const _Float16* __restrict__ qk,
                                              const _Float16* __restrict__ vt,
                                              _Float16* __restrict__ ctx) {
  const int qt = blockIdx.x, h = blockIdx.y, b = blockIdx.z;
  const int t = threadIdx.x, w = t >> 6, lane = t & 63;
  const int c16 = lane & 15, g = lane >> 4;
  const int q0 = qt * 64;
  const _Float16* Qp = qk + (size_t)b * 2048 * 2048 + h * 64;
  const _Float16* Kp = Qp + 1024;
  const _Float16* Vt = vt + ((size_t)b * 1024 + h * 64) * 2048;

  __shared__ _Float16 Pls[4][16][72];  // per-wave P buffer (stride 144B, 16B aligned)

  const int qrow = q0 + w * 16;
  const f16x8 qf0 = *reinterpret_cast<const f16x8*>(Qp + (size_t)(qrow + c16) * 2048 + g * 8);
  const f16x8 qf1 = *reinterpret_cast<const f16x8*>(Qp + (size_t)(qrow + c16) * 2048 + 32 + g * 8);

  f32x4 o[4] = {};
  float m[4], l[4];
#pragma unroll
  for (int j = 0; j < 4; ++j) { m[j] = -__builtin_inff(); l[j] = 0.f; }
  const int racc = qrow + g * 4;  // + j  = this lane's accumulator rows
  constexpr float SC = 0.125f;            // 1/sqrt(64)
  constexpr float L2E = 1.4426950408889634f;

  for (int kt = 0; kt <= qt; ++kt) {
    const int kb = kt * 64;
    // S = Q K^T  (16 q-rows x 64 k-cols per wave)
    f32x4 s[4] = {};
#pragma unroll
    for (int n = 0; n < 4; ++n) {
      const _Float16* krow = Kp + (size_t)(kb + n * 16 + c16) * 2048;
      s[n] = mfma16(qf0, *reinterpret_cast<const f16x8*>(krow + g * 8), s[n]);
      s[n] = mfma16(qf1, *reinterpret_cast<const f16x8*>(krow + 32 + g * 8), s[n]);
    }
    // scale + causal mask + online softmax
    float tmax[4] = {-__builtin_inff(), -__builtin_inff(), -__builtin_inff(), -__builtin_inff()};
    const bool diag = (kt == qt);
#pragma unroll
    for (int n = 0; n < 4; ++n) {
#pragma unroll
      for (int j = 0; j < 4; ++j) {
        float v = s[n][j] * SC;
        if (diag && (kb + n * 16 + c16 > racc + j)) v = -__builtin_inff();
        s[n][j] = v;
        tmax[j] = fmaxf(tmax[j], v);
      }
    }
#pragma unroll
    for (int off = 1; off < 16; off <<= 1) {
#pragma unroll
      for (int j = 0; j < 4; ++j)
        tmax[j] = fmaxf(tmax[j], __shfl_xor(tmax[j], off, 64));
    }
#pragma unroll
    for (int j = 0; j < 4; ++j) {
      const float mn = fmaxf(m[j], tmax[j]);
      const float fac = exp2f((m[j] - mn) * L2E);
      m[j] = mn;
      l[j] *= fac;
#pragma unroll
      for (int n = 0; n < 4; ++n) {
        o[n][j] *= fac;
        const float p = exp2f((s[n][j] - mn) * L2E);
        l[j] += p;
        Pls[w][g * 4 + j][n * 16 + c16] = (_Float16)p;
      }
    }
    // PV: o += P @ V   (V^T rows are k-contiguous -> direct global b-frags)
    const f16x8 pf0 = *reinterpret_cast<const f16x8*>(&Pls[w][c16][g * 8]);
    const f16x8 pf1 = *reinterpret_cast<const f16x8*>(&Pls[w][c16][32 + g * 8]);
#pragma unroll
    for (int n = 0; n < 4; ++n) {
      const _Float16* vrow = Vt + (size_t)(n * 16 + c16) * 2048 + kb;
      o[n] = mfma16(pf0, *reinterpret_cast<const f16x8*>(vrow + g * 8), o[n]);
      o[n] = mfma16(pf1, *reinterpret_cast<const f16x8*>(vrow + 32 + g * 8), o[n]);
    }
  }
  // final l reduction across the 16 lanes holding each row
#pragma unroll
  for (int off = 1; off < 16; off <<= 1) {
#pragma unroll
    for (int j = 0; j < 4; ++j) l[j] += __shfl_xor(l[j], off, 64);
  }
#pragma unroll
  for (int j = 0; j < 4; ++j) {
    const float rl = 1.f / l[j];
    _Float16* crow = ctx + (size_t)(b * 2048 + racc + j) * 1024 + h * 64;
#pragma unroll
    for (int n = 0; n < 4; ++n) crow[n * 16 + c16] = (_Float16)(o[n][j] * rl);
  }
}

// ---------------- launcher ----------------
extern "C" void kernel_launch(void* const* d_in, const int* in_sizes, int n_in,
                              void* d_out, int out_size, void* d_ws, size_t ws_size,
                              hipStream_t stream) {
  (void)in_sizes; (void)n_in; (void)out_size; (void)ws_size;
  const float* x  = (const float*)d_in[0];
  const float* Wq = (const float*)d_in[1];
  const float* Wk = (const float*)d_in[2];
  const float* Wv = (const float*)d_in[3];
  const float* Wo = (const float*)d_in[4];
  const float* bo = (const float*)d_in[5];
  float* out = (float*)d_out;

  char* ws = (char*)d_ws;
  _Float16* xb    = (_Float16*)(ws);                 //  8 MB  x fp16 [4096][1024]
  _Float16* wqkvt = (_Float16*)(ws + (8u  << 20));   //  6 MB  [Wq^T;Wk^T;Wv^T] [3072][1024]
  _Float16* wot   = (_Float16*)(ws + (14u << 20));   //  2 MB  Wo^T [1024][1024]
  _Float16* qkb   = (_Float16*)(ws + (16u << 20));   // 16 MB  QK [4096][2048]
  _Float16* vtb   = (_Float16*)(ws + (32u << 20));   //  8 MB  V^T [2][1024][2048]
  _Float16* ctx   = (_Float16*)(ws + (40u << 20));   //  8 MB  ctx [4096][1024]

  k_cvt_f16<<<4096, 256, 0, stream>>>(x, xb);
  dim3 tg(32, 32);
  k_transpose_f16<<<tg, 256, 0, stream>>>(Wq, wqkvt);
  k_transpose_f16<<<tg, 256, 0, stream>>>(Wk, wqkvt + (1u << 20));
  k_transpose_f16<<<tg, 256, 0, stream>>>(Wv, wqkvt + (2u << 20));
  k_transpose_f16<<<tg, 256, 0, stream>>>(Wo, wot);

  k_gemm<0><<<dim3(24, 32), 256, 0, stream>>>(xb, wqkvt, nullptr, qkb, vtb, nullptr, 3072, 1024);
  k_attn<<<dim3(32, 16, 2), 256, 0, stream>>>(qkb, vtb, ctx);
  k_gemm<1><<<dim3(8, 32), 256, 0, stream>>>(ctx, wot, bo, nullptr, nullptr, out, 1024, 1024);
}

// Round 2
// 198.713 us; speedup vs baseline: 1.5798x; 1.5798x over previous
//
#include <hip/hip_runtime.h>
#include <stdint.h>

typedef _Float16 __attribute__((ext_vector_type(8))) f16x8;
typedef _Float16 __attribute__((ext_vector_type(4))) f16x4v;
typedef float __attribute__((ext_vector_type(4))) f32x4;

__device__ __forceinline__ f32x4 mfma16(f16x8 a, f16x8 b, f32x4 c) {
  return __builtin_amdgcn_mfma_f32_16x16x32_f16(a, b, c, 0, 0, 0);
}

// async global->LDS, 16B per lane. lds must be wave-uniform base; HW adds lane*16.
__device__ __forceinline__ void async16(void* lds, const void* g) {
  __builtin_amdgcn_global_load_lds((const __attribute__((address_space(1))) void*)g,
                                   (__attribute__((address_space(3))) void*)lds, 16, 0, 0);
}

// ---------------- conversions ----------------
__global__ __launch_bounds__(256) void k_cvt_f16(const float* __restrict__ in,
                                                 _Float16* __restrict__ out) {
  const int i = blockIdx.x * 256 + threadIdx.x;
  const float4 v = reinterpret_cast<const float4*>(in)[i];
  f16x4v o = { (_Float16)v.x, (_Float16)v.y, (_Float16)v.z, (_Float16)v.w };
  reinterpret_cast<f16x4v*>(out)[i] = o;
}

// W[1024][1024] f32 -> Wt[1024][1024] f16 with Wt[n][k] = W[k][n]
__global__ __launch_bounds__(256) void k_transpose_f16(const float* __restrict__ W,
                                                       _Float16* __restrict__ Wt) {
  __shared__ float tl[32][33];
  const int c0 = blockIdx.x * 32, r0 = blockIdx.y * 32;
  const int tx = threadIdx.x & 31, ty = threadIdx.x >> 5;  // 32 x 8
#pragma unroll
  for (int i = 0; i < 32; i += 8)
    tl[ty + i][tx] = W[(size_t)(r0 + ty + i) * 1024 + c0 + tx];
  __syncthreads();
#pragma unroll
  for (int i = 0; i < 32; i += 8)
    Wt[(size_t)(c0 + ty + i) * 1024 + r0 + tx] = (_Float16)tl[tx][ty + i];
}

// ---------------- GEMM: C[M][N] = A[M][K] @ Bt[N][K]^T ----------------
// LDS layout per matrix: [g][128 rows][8 f16] (g = 16B k-chunk), linear for
// global_load_lds; frag reads are lane-contiguous (conflict-free).
// MODE 0: f16 out, split qk (cols<2048) / V^T (cols>=2048). MODE 1: f32+bias.
template <int MODE>
__global__ __launch_bounds__(256) void k_gemm(const _Float16* __restrict__ A,
                                              const _Float16* __restrict__ Bt,
                                              const float* __restrict__ bias,
                                              _Float16* __restrict__ qkout,
                                              _Float16* __restrict__ vtout,
                                              float* __restrict__ fout,
                                              int N, int K) {
  __shared__ _Float16 As[4096];
  __shared__ _Float16 Bs[4096];
  const int tile_n = blockIdx.x * 128;
  const int tile_m = blockIdx.y * 128;
  const int t = threadIdx.x;
  const int w = t >> 6, lane = t & 63;
  const int c16 = lane & 15, g = lane >> 4;
  const int wr = (w >> 1) * 64, wc = (w & 1) * 64;

  f32x4 acc[4][4] = {};

  for (int k0 = 0; k0 < K; k0 += 32) {
    __syncthreads();
#pragma unroll
    for (int i = 0; i < 2; ++i) {
      const int beta = i * 4096 + t * 16;            // linear LDS byte this lane fills
      const int gg = beta >> 11, row = (beta >> 4) & 127;
      async16(&As[i * 2048 + w * 512], A + (size_t)(tile_m + row) * K + k0 + gg * 8);
      async16(&Bs[i * 2048 + w * 512], Bt + (size_t)(tile_n + row) * K + k0 + gg * 8);
    }
    __syncthreads();  // drains vmcnt(0): staged data visible
    f16x8 af[4], bf[4];
#pragma unroll
    for (int i = 0; i < 4; ++i) {
      af[i] = *reinterpret_cast<const f16x8*>(&As[g * 1024 + (wr + i * 16 + c16) * 8]);
      bf[i] = *reinterpret_cast<const f16x8*>(&Bs[g * 1024 + (wc + i * 16 + c16) * 8]);
    }
#pragma unroll
    for (int i = 0; i < 4; ++i)
#pragma unroll
      for (int j = 0; j < 4; ++j) acc[i][j] = mfma16(af[i], bf[j], acc[i][j]);
  }

  // D layout: col = lane&15, row = (lane>>4)*4 + reg
#pragma unroll
  for (int i = 0; i < 4; ++i) {
#pragma unroll
    for (int j = 0; j < 4; ++j) {
      const int colb = tile_n + wc + j * 16;
#pragma unroll
      for (int r = 0; r < 4; ++r) {
        const int row = tile_m + wr + i * 16 + g * 4 + r;
        const int col = colb + c16;
        const float v = acc[i][j][r];
        if constexpr (MODE == 0) {
          if (col < 2048) {
            qkout[(size_t)row * 2048 + col] = (_Float16)v;
          } else {
            const int dd = col - 2048;  // h*64 + d
            vtout[((size_t)(row >> 11) * 1024 + dd) * 2048 + (row & 2047)] = (_Float16)v;
          }
        } else {
          fout[(size_t)row * N + col] = v + bias[col];
        }
      }
    }
  }
}

// ---------------- causal flash attention (paired q-tiles, LDS-staged K/V) ----
constexpr float SCALE = 0.125f;  // 1/sqrt(64)
constexpr float L2E = 1.4426950408889634f;

__device__ __forceinline__ void qkmm(const f16x8* qf, const f16x8 bf[4][2], f32x4* s) {
#pragma unroll
  for (int n = 0; n < 4; ++n) {
    s[n] = mfma16(qf[0], bf[n][0], s[n]);
    s[n] = mfma16(qf[1], bf[n][1], s[n]);
  }
}

__device__ __forceinline__ void sm_pv(f32x4* s, f32x4* o, float* m, float* l,
                                      _Float16* P, const f16x8 vf[4][2],
                                      int racc, int kb, bool diag, int c16, int g) {
  float tmax[4] = {-__builtin_inff(), -__builtin_inff(), -__builtin_inff(), -__builtin_inff()};
#pragma unroll
  for (int n = 0; n < 4; ++n)
#pragma unroll
    for (int j = 0; j < 4; ++j) {
      float v = s[n][j] * SCALE;
      if (diag && (kb + n * 16 + c16 > racc + j)) v = -__builtin_inff();
      s[n][j] = v;
      tmax[j] = fmaxf(tmax[j], v);
    }
#pragma unroll
  for (int off = 1; off < 16; off <<= 1)
#pragma unroll
    for (int j = 0; j < 4; ++j) tmax[j] = fmaxf(tmax[j], __shfl_xor(tmax[j], off, 64));
#pragma unroll
  for (int j = 0; j < 4; ++j) {
    const float mn = fmaxf(m[j], tmax[j]);
    const float fac = exp2f((m[j] - mn) * L2E);
    m[j] = mn;
    l[j] *= fac;
#pragma unroll
    for (int n = 0; n < 4; ++n) {
      o[n][j] *= fac;
      const float p = exp2f((s[n][j] - mn) * L2E);
      l[j] += p;
      P[(g * 4 + j) * 72 + n * 16 + c16] = (_Float16)p;
    }
  }
  const f16x8 pf0 = *reinterpret_cast<const f16x8*>(&P[c16 * 72 + g * 8]);
  const f16x8 pf1 = *reinterpret_cast<const f16x8*>(&P[c16 * 72 + 32 + g * 8]);
#pragma unroll
  for (int n = 0; n < 4; ++n) {
    o[n] = mfma16(pf0, vf[n][0], o[n]);
    o[n] = mfma16(pf1, vf[n][1], o[n]);
  }
}

// qk: [b*2048][2048] f16 (Q cols 0..1023, K cols 1024..2047), vt: [b][h*64+d][2048]
// Block = (pair, h, b): processes q-tiles qA=31-pr and qB=pr over one kv sweep.
__global__ __launch_bounds__(256, 2) void k_attn(const _Float16* __restrict__ qk,
                                                 const _Float16* __restrict__ vt,
                                                 _Float16* __restrict__ ctx) {
  const int pr = blockIdx.x, h = blockIdx.y, b = blockIdx.z;
  const int qA = 31 - pr, qB = pr;
  const int t = threadIdx.x, w = t >> 6, lane = t & 63;
  const int c16 = lane & 15, g = lane >> 4;
  const _Float16* Qp = qk + (size_t)b * 2048 * 2048 + h * 64;
  const _Float16* Kp = Qp + 1024;
  const _Float16* Vt = vt + ((size_t)b * 1024 + h * 64) * 2048;

  __shared__ _Float16 Kl[2][4096];   // [buf]: [kh][g][64 rows][8 f16]
  __shared__ _Float16 Vl[2][4096];
  __shared__ _Float16 Pls[4][16 * 72];

  const int rowA = qA * 64 + w * 16, rowB = qB * 64 + w * 16;
  f16x8 qfA[2], qfB[2];
#pragma unroll
  for (int kh = 0; kh < 2; ++kh) {
    qfA[kh] = *reinterpret_cast<const f16x8*>(Qp + (size_t)(rowA + c16) * 2048 + kh * 32 + g * 8);
    qfB[kh] = *reinterpret_cast<const f16x8*>(Qp + (size_t)(rowB + c16) * 2048 + kh * 32 + g * 8);
  }

  auto stage = [&](int buf, int kb) {
#pragma unroll
    for (int i = 0; i < 2; ++i) {
      const int beta = i * 4096 + t * 16;
      const int kh = beta >> 12, gg = (beta >> 10) & 3, row = (beta >> 4) & 63;
      const int soff = kh * 32 + gg * 8;
      async16(&Kl[buf][i * 2048 + w * 512], Kp + (size_t)(kb + row) * 2048 + soff);
      async16(&Vl[buf][i * 2048 + w * 512], Vt + (size_t)row * 2048 + kb + soff);
    }
  };

  f32x4 oA[4] = {}, oB[4] = {};
  float mA[4], lA[4], mB[4], lB[4];
#pragma unroll
  for (int j = 0; j < 4; ++j) {
    mA[j] = -__builtin_inff(); lA[j] = 0.f;
    mB[j] = -__builtin_inff(); lB[j] = 0.f;
  }

  stage(0, 0);
  __syncthreads();

  for (int kt = 0; kt <= qA; ++kt) {
    const int buf = kt & 1;
    if (kt < qA) stage(buf ^ 1, (kt + 1) * 64);  // prefetch overlaps compute
    const int kb = kt * 64;
    f16x8 bf[4][2], vf[4][2];
#pragma unroll
    for (int n = 0; n < 4; ++n)
#pragma unroll
      for (int kh = 0; kh < 2; ++kh) {
        bf[n][kh] = *reinterpret_cast<const f16x8*>(&Kl[buf][kh * 2048 + g * 512 + (n * 16 + c16) * 8]);
        vf[n][kh] = *reinterpret_cast<const f16x8*>(&Vl[buf][kh * 2048 + g * 512 + (n * 16 + c16) * 8]);
      }
    f32x4 sA[4] = {}, sB[4] = {};
    qkmm(qfA, bf, sA);
    const bool actB = (kt <= qB);
    if (actB) qkmm(qfB, bf, sB);
    sm_pv(sA, oA, mA, lA, &Pls[w][0], vf, rowA + g * 4, kb, kt == qA, c16, g);
    if (actB) sm_pv(sB, oB, mB, lB, &Pls[w][0], vf, rowB + g * 4, kb, kt == qB, c16, g);
    __syncthreads();  // drains prefetch vmcnt + guards buffer reuse
  }

#pragma unroll
  for (int off = 1; off < 16; off <<= 1)
#pragma unroll
    for (int j = 0; j < 4; ++j) {
      lA[j] += __shfl_xor(lA[j], off, 64);
      lB[j] += __shfl_xor(lB[j], off, 64);
    }
#pragma unroll
  for (int j = 0; j < 4; ++j) {
    const float rlA = 1.f / lA[j], rlB = 1.f / lB[j];
    _Float16* ca = ctx + (size_t)(b * 2048 + rowA + g * 4 + j) * 1024 + h * 64;
    _Float16* cb = ctx + (size_t)(b * 2048 + rowB + g * 4 + j) * 1024 + h * 64;
#pragma unroll
    for (int n = 0; n < 4; ++n) {
      ca[n * 16 + c16] = (_Float16)(oA[n][j] * rlA);
      cb[n * 16 + c16] = (_Float16)(oB[n][j] * rlB);
    }
  }
}

// ---------------- launcher ----------------
extern "C" void kernel_launch(void* const* d_in, const int* in_sizes, int n_in,
                              void* d_out, int out_size, void* d_ws, size_t ws_size,
                              hipStream_t stream) {
  (void)in_sizes; (void)n_in; (void)out_size; (void)ws_size;
  const float* x  = (const float*)d_in[0];
  const float* Wq = (const float*)d_in[1];
  const float* Wk = (const float*)d_in[2];
  const float* Wv = (const float*)d_in[3];
  const float* Wo = (const float*)d_in[4];
  const float* bo = (const float*)d_in[5];
  float* out = (float*)d_out;

  char* ws = (char*)d_ws;
  _Float16* xb    = (_Float16*)(ws);                 //  8 MB  x fp16 [4096][1024]
  _Float16* wqkvt = (_Float16*)(ws + (8u  << 20));   //  6 MB  [Wq^T;Wk^T;Wv^T]
  _Float16* wot   = (_Float16*)(ws + (14u << 20));   //  2 MB  Wo^T
  _Float16* qkb   = (_Float16*)(ws + (16u << 20));   // 16 MB  QK [4096][2048]
  _Float16* vtb   = (_Float16*)(ws + (32u << 20));   //  8 MB  V^T [2][1024][2048]
  _Float16* ctx   = (_Float16*)(ws + (40u << 20));   //  8 MB  ctx [4096][1024]

  k_cvt_f16<<<4096, 256, 0, stream>>>(x, xb);
  dim3 tg(32, 32);
  k_transpose_f16<<<tg, 256, 0, stream>>>(Wq, wqkvt);
  k_transpose_f16<<<tg, 256, 0, stream>>>(Wk, wqkvt + (1u << 20));
  k_transpose_f16<<<tg, 256, 0, stream>>>(Wv, wqkvt + (2u << 20));
  k_transpose_f16<<<tg, 256, 0, stream>>>(Wo, wot);

  k_gemm<0><<<dim3(24, 32), 256, 0, stream>>>(xb, wqkvt, nullptr, qkb, vtb, nullptr, 3072, 1024);
  k_attn<<<dim3(16, 16, 2), 256, 0, stream>>>(qkb, vtb, ctx);
  k_gemm<1><<<dim3(8, 32), 256, 0, stream>>>(ctx, wot, bo, nullptr, nullptr, out, 1024, 1024);
}

// Round 4
// 193.293 us; speedup vs baseline: 1.6241x; 1.0280x over previous
//
#include <hip/hip_runtime.h>
#include <stdint.h>

typedef _Float16 __attribute__((ext_vector_type(8))) f16x8;
typedef _Float16 __attribute__((ext_vector_type(4))) f16x4v;
typedef float __attribute__((ext_vector_type(4))) f32x4;
typedef float __attribute__((ext_vector_type(16))) f32x16;

__device__ __forceinline__ f32x4 mfma16(f16x8 a, f16x8 b, f32x4 c) {
  return __builtin_amdgcn_mfma_f32_16x16x32_f16(a, b, c, 0, 0, 0);
}
__device__ __forceinline__ f32x16 mfma32(f16x8 a, f16x8 b, f32x16 c) {
  return __builtin_amdgcn_mfma_f32_32x32x16_f16(a, b, c, 0, 0, 0);
}

// async global->LDS, 16B per lane. lds base wave-uniform; HW adds lane*16.
__device__ __forceinline__ void async16(void* lds, const void* g) {
  __builtin_amdgcn_global_load_lds((const __attribute__((address_space(1))) void*)g,
                                   (__attribute__((address_space(3))) void*)lds, 16, 0, 0);
}

#define QK_PRESCALE 0.18033688011112042f  // (1/sqrt(64)) * log2(e)

// ---------------- conversions ----------------
__global__ __launch_bounds__(256) void k_cvt_f16(const float* __restrict__ in,
                                                 _Float16* __restrict__ out) {
  const int i = blockIdx.x * 256 + threadIdx.x;
  const float4 v = reinterpret_cast<const float4*>(in)[i];
  f16x4v o = { (_Float16)v.x, (_Float16)v.y, (_Float16)v.z, (_Float16)v.w };
  reinterpret_cast<f16x4v*>(out)[i] = o;
}

// 4 weight transposes in one launch. z=0..2 -> wqkvt rows z*1024.., z=3 -> wot
__global__ __launch_bounds__(256) void k_transpose_all(
    const float* __restrict__ Wq, const float* __restrict__ Wk,
    const float* __restrict__ Wv, const float* __restrict__ Wo,
    _Float16* __restrict__ wqkvt, _Float16* __restrict__ wot) {
  __shared__ float tl[32][33];
  const int z = blockIdx.z;
  const float* W = (z == 0) ? Wq : (z == 1) ? Wk : (z == 2) ? Wv : Wo;
  _Float16* dst = (z < 3) ? (wqkvt + ((size_t)z << 20)) : wot;
  const int c0 = blockIdx.x * 32, r0 = blockIdx.y * 32;
  const int tx = threadIdx.x & 31, ty = threadIdx.x >> 5;  // 32 x 8
#pragma unroll
  for (int i = 0; i < 32; i += 8)
    tl[ty + i][tx] = W[(size_t)(r0 + ty + i) * 1024 + c0 + tx];
  __syncthreads();
#pragma unroll
  for (int i = 0; i < 32; i += 8)
    dst[(size_t)(c0 + ty + i) * 1024 + r0 + tx] = (_Float16)tl[tx][ty + i];
}

// ---------------- GEMM: C[M][N] = A[M][K] @ Bt[N][K]^T ----------------
// LDS per matrix: [g4][128 rows][8 f16]; linear for global_load_lds,
// lane-contiguous conflict-free frag reads. Double-buffered, 1 barrier/step.
// MODE 0: f16 out -> qk (cols<2048, Q cols prescaled) / V^T (cols>=2048).
// MODE 1: f32 out + bias.
template <int MODE>
__global__ __launch_bounds__(256) void k_gemm(const _Float16* __restrict__ A,
                                              const _Float16* __restrict__ Bt,
                                              const float* __restrict__ bias,
                                              _Float16* __restrict__ qkout,
                                              _Float16* __restrict__ vtout,
                                              float* __restrict__ fout,
                                              int N, int K) {
  __shared__ _Float16 As[2][4096];
  __shared__ _Float16 Bs[2][4096];
  // bijective XCD swizzle (grid total % 8 == 0 for both uses)
  const int nbx = gridDim.x;
  const int fid = blockIdx.y * nbx + blockIdx.x;
  const int cpx = (nbx * gridDim.y) >> 3;
  const int swz = (fid & 7) * cpx + (fid >> 3);
  const int tile_n = (swz % nbx) * 128;
  const int tile_m = (swz / nbx) * 128;
  const int t = threadIdx.x;
  const int w = t >> 6, lane = t & 63;
  const int c16 = lane & 15, g = lane >> 4;
  const int wr = (w >> 1) * 64, wc = (w & 1) * 64;

  f32x4 acc[4][4] = {};

  auto stage = [&](int buf, int k0) {
#pragma unroll
    for (int i = 0; i < 2; ++i) {
      const int u = i * 256 + t;               // 16B unit index 0..511
      const int gg = u >> 7, row = u & 127;
      async16(&As[buf][(i * 256 + w * 64) * 8], A + (size_t)(tile_m + row) * K + k0 + gg * 8);
      async16(&Bs[buf][(i * 256 + w * 64) * 8], Bt + (size_t)(tile_n + row) * K + k0 + gg * 8);
    }
  };

  stage(0, 0);
  const int nsteps = K >> 5;
  for (int it = 0; it < nsteps; ++it) {
    const int buf = it & 1;
    __syncthreads();                            // staged data ready; prev reads done
    if (it + 1 < nsteps) stage(buf ^ 1, (it + 1) << 5);
    f16x8 af[4], bf[4];
#pragma unroll
    for (int i = 0; i < 4; ++i) {
      af[i] = *reinterpret_cast<const f16x8*>(&As[buf][g * 1024 + (wr + i * 16 + c16) * 8]);
      bf[i] = *reinterpret_cast<const f16x8*>(&Bs[buf][g * 1024 + (wc + i * 16 + c16) * 8]);
    }
#pragma unroll
    for (int i = 0; i < 4; ++i)
#pragma unroll
      for (int j = 0; j < 4; ++j) acc[i][j] = mfma16(af[i], bf[j], acc[i][j]);
  }

  // D layout: col = lane&15, row = (lane>>4)*4 + reg
#pragma unroll
  for (int i = 0; i < 4; ++i) {
#pragma unroll
    for (int j = 0; j < 4; ++j) {
      const int colb = tile_n + wc + j * 16;
#pragma unroll
      for (int r = 0; r < 4; ++r) {
        const int row = tile_m + wr + i * 16 + g * 4 + r;
        const int col = colb + c16;
        float v = acc[i][j][r];
        if constexpr (MODE == 0) {
          if (col < 2048) {
            if (col < 1024) v *= QK_PRESCALE;   // fold softmax scale into Q
            qkout[(size_t)row * 2048 + col] = (_Float16)v;
          } else {
            const int dd = col - 2048;  // h*64 + d
            vtout[((size_t)(row >> 11) * 1024 + dd) * 2048 + (row & 2047)] = (_Float16)v;
          }
        } else {
          fout[(size_t)row * N + col] = v + bias[col];
        }
      }
    }
  }
}

// ---------------- causal flash attention, swapped-operand 32x32 ----------------
// qk: [b*2048][2048] f16 (Q cols 0..1023 prescaled, K cols 1024..2047)
// vt: [b][h*64+d][2048] f16;  ctx: [b*2048][1024] f16
// Block: 4 waves x 32 q-rows = 128-row q-tile. KVBLK=64, dbuf LDS staging.
// S^T = mfma(K,Q): lane owns q-col (q = qtile + w*32 + (lane&31)); softmax lane-local.
__global__ __launch_bounds__(256, 2) void k_attn(const _Float16* __restrict__ qk,
                                                 const _Float16* __restrict__ vt,
                                                 _Float16* __restrict__ ctx) {
  // remap: same (h,b) -> same XCD slot; heavy q-tiles first
  const int fid = blockIdx.x + (blockIdx.y << 4) + (blockIdx.z << 8);
  const int xcd = fid & 7, s = fid >> 3;
  const int grp = xcd + ((s >> 4) << 3);        // 0..31 = h + 16*b
  const int h = grp & 15, b = grp >> 4;
  const int qt = 15 - (s & 15);                 // heavy first
  const int t = threadIdx.x, w = t >> 6, lane = t & 63;
  const int li = lane & 31, hi = lane >> 5;

  const _Float16* Qp = qk + ((size_t)b << 22) + (h << 6);
  const _Float16* Kp = Qp + 1024;
  const _Float16* Vt = vt + ((((size_t)b << 10) + (size_t)(h << 6)) << 11);

  __shared__ _Float16 Kl[2][4096];  // [m4][hi2][kpos64][8f16] (16B unit = m*128+hi*64+kpos)
  __shared__ _Float16 Vl[2][4096];  // [chunk4][hi2][d64][8f16]

  const int qrow = (qt << 7) + (w << 5) + li;   // this lane's q row
  f16x8 qf[4];
#pragma unroll
  for (int mm = 0; mm < 4; ++mm)
    qf[mm] = *reinterpret_cast<const f16x8*>(Qp + (size_t)qrow * 2048 + mm * 16 + hi * 8);

  auto stage = [&](int buf, int kt) {
    const int kb = kt << 6;
#pragma unroll
    for (int j = 0; j < 4; ++j) {
      const int c = w * 4 + j;
      if (c < 8) {
        const int mm = c >> 1, hh = c & 1;
        async16(&Kl[buf][c * 512], Kp + (size_t)(kb + lane) * 2048 + mm * 16 + hh * 8);
      } else {
        const int cc = c - 8, mm = cc >> 1, hh = cc & 1;
        async16(&Vl[buf][cc * 512], Vt + (size_t)lane * 2048 + kb + mm * 16 + hh * 8);
      }
    }
  };

  f32x16 oa[2];
#pragma unroll
  for (int sd = 0; sd < 2; ++sd)
#pragma unroll
    for (int r = 0; r < 16; ++r) oa[sd][r] = 0.f;
  float mval = -3e38f, lsum = 0.f;

  const int nkv = (qt << 1) + 2;
  stage(0, 0);

  for (int kt = 0; kt < nkv; ++kt) {
    const int buf = kt & 1;
    const int kb = kt << 6;
    const int qmin = (qt << 7) + (w << 5);
    const bool act0 = kb <= qmin + 31;
    const bool act1 = kb + 32 <= qmin + 31;
    __syncthreads();                             // staged buf ready; prev reads done
    if (kt + 1 < nkv) stage(buf ^ 1, kt + 1);

    if (act0) {
      const int nsub = act1 ? 2 : 1;
      f32x16 st[2] = {};
      // S^T = K * Q^T
#pragma unroll
      for (int sub = 0; sub < 2; ++sub)
        if (sub < nsub)
#pragma unroll
          for (int mm = 0; mm < 4; ++mm) {
            const f16x8 kf = *reinterpret_cast<const f16x8*>(
                &Kl[buf][(mm * 128 + hi * 64 + sub * 32 + li) * 8]);
            st[sub] = mfma32(kf, qf[mm], st[sub]);
          }
      // mask + lane-local row max (values already in log2 domain via Q prescale)
      float tm = -3e38f;
#pragma unroll
      for (int sub = 0; sub < 2; ++sub)
        if (sub < nsub) {
          const bool nm = (kb + sub * 32 + 31 > qmin);   // overlaps diagonal
#pragma unroll
          for (int r = 0; r < 16; ++r) {
            float v = st[sub][r];
            if (nm) {
              const int k_abs = kb + sub * 32 + (r & 3) + ((r >> 2) << 3) + (hi << 2);
              if (k_abs > qrow) v = -3e38f;
            }
            st[sub][r] = v;
            tm = fmaxf(tm, v);
          }
        }
      tm = fmaxf(tm, __shfl_xor(tm, 32));
      // defer-max rescale (THR = 8)
      if (__any(tm > mval + 8.f)) {
        const float mn = fmaxf(mval, tm);
        const float fac = exp2f(mval - mn);
#pragma unroll
        for (int sd = 0; sd < 2; ++sd)
#pragma unroll
          for (int r = 0; r < 16; ++r) oa[sd][r] *= fac;
        lsum *= fac;
        mval = mn;
      }
      // p = exp2(s - m); pack to f16 pairs; redistribute; PV
#pragma unroll
      for (int sub = 0; sub < 2; ++sub)
        if (sub < nsub) {
          unsigned G[8];
#pragma unroll
          for (int j = 0; j < 8; ++j) {
            const float p0 = exp2f(st[sub][2 * j] - mval);
            const float p1 = exp2f(st[sub][2 * j + 1] - mval);
            lsum += p0 + p1;
            G[j] = __builtin_bit_cast(unsigned, __builtin_amdgcn_cvt_pkrtz(p0, p1));
          }
#pragma unroll
          for (int half = 0; half < 2; ++half) {
            const unsigned g0 = G[half * 4 + 0], g1 = G[half * 4 + 1];
            const unsigned g2 = G[half * 4 + 2], g3 = G[half * 4 + 3];
            const unsigned s02 = __shfl_xor(hi ? g0 : g2, 32);
            const unsigned s13 = __shfl_xor(hi ? g1 : g3, 32);
            union { unsigned u[4]; f16x8 v; } pb;
            pb.u[0] = hi ? s02 : g0;
            pb.u[1] = hi ? s13 : g1;
            pb.u[2] = hi ? g2 : s02;
            pb.u[3] = hi ? g3 : s13;
            const int chunk = sub * 2 + half;
#pragma unroll
            for (int sd = 0; sd < 2; ++sd) {
              const f16x8 vf = *reinterpret_cast<const f16x8*>(
                  &Vl[buf][(chunk * 128 + hi * 64 + sd * 32 + li) * 8]);
              oa[sd] = mfma32(vf, pb.v, oa[sd]);
            }
          }
        }
    }
  }

  // finalize: l across the lane pair, normalize, write ctx
  const float lt = lsum + __shfl_xor(lsum, 32);
  const float rl = 1.f / lt;
  _Float16* crow = ctx + (((size_t)(b * 2048 + qrow)) << 10) + (h << 6);
#pragma unroll
  for (int sd = 0; sd < 2; ++sd)
#pragma unroll
    for (int rr = 0; rr < 4; ++rr) {
      const int d0 = sd * 32 + rr * 8 + hi * 4;
      uint2 pr;
      pr.x = __builtin_bit_cast(unsigned, __builtin_amdgcn_cvt_pkrtz(
                 oa[sd][rr * 4 + 0] * rl, oa[sd][rr * 4 + 1] * rl));
      pr.y = __builtin_bit_cast(unsigned, __builtin_amdgcn_cvt_pkrtz(
                 oa[sd][rr * 4 + 2] * rl, oa[sd][rr * 4 + 3] * rl));
      *reinterpret_cast<uint2*>(crow + d0) = pr;
    }
}

// ---------------- launcher ----------------
extern "C" void kernel_launch(void* const* d_in, const int* in_sizes, int n_in,
                              void* d_out, int out_size, void* d_ws, size_t ws_size,
                              hipStream_t stream) {
  (void)in_sizes; (void)n_in; (void)out_size; (void)ws_size;
  const float* x  = (const float*)d_in[0];
  const float* Wq = (const float*)d_in[1];
  const float* Wk = (const float*)d_in[2];
  const float* Wv = (const float*)d_in[3];
  const float* Wo = (const float*)d_in[4];
  const float* bo = (const float*)d_in[5];
  float* out = (float*)d_out;

  char* ws = (char*)d_ws;
  _Float16* xb    = (_Float16*)(ws);                 //  8 MB  x f16 [4096][1024]
  _Float16* wqkvt = (_Float16*)(ws + (8u  << 20));   //  6 MB  [Wq^T;Wk^T;Wv^T]
  _Float16* wot   = (_Float16*)(ws + (14u << 20));   //  2 MB  Wo^T
  _Float16* qkb   = (_Float16*)(ws + (16u << 20));   // 16 MB  QK [4096][2048]
  _Float16* vtb   = (_Float16*)(ws + (32u << 20));   //  8 MB  V^T [2][1024][2048]
  _Float16* ctx   = (_Float16*)(ws + (40u << 20));   //  8 MB  ctx [4096][1024]

  k_cvt_f16<<<4096, 256, 0, stream>>>(x, xb);
  k_transpose_all<<<dim3(32, 32, 4), 256, 0, stream>>>(Wq, Wk, Wv, Wo, wqkvt, wot);
  k_gemm<0><<<dim3(24, 32), 256, 0, stream>>>(xb, wqkvt, nullptr, qkb, vtb, nullptr, 3072, 1024);
  k_attn<<<dim3(16, 16, 2), 256, 0, stream>>>(qkb, vtb, ctx);
  k_gemm<1><<<dim3(8, 32), 256, 0, stream>>>(ctx, wot, bo, nullptr, nullptr, out, 1024, 1024);
}